// Round 19
// baseline (89.961 us; speedup 1.0000x reference)
//
#include <hip/hip_runtime.h>
#include <math.h>

// ---- all scratch as device globals ----
__device__ float  g_norms[16];
__device__ float  g_partial[1024];
__device__ float  g_phs[65536];
__device__ float2 g_cs[65536];
__device__ float  g_FW1[256*32];       // Fx@W1 + (gb0@W1 + gb1), per column c
__device__ float  g_GW1[256*32];       // Gy@W1, per row r
__device__ float  g_I[65536];
__device__ float2 g_tw[512];
__device__ float2 g_SfA[256*512];
__device__ float2 g_Sf [512*512];
__device__ float2 g_F  [16*256*256];
__device__ float2 g_KA [8*256*512];
__device__ float2 g_P  [8*256*512];

__device__ __forceinline__ int rev4d8(int x){
  return ((x&3)<<6) | (((x>>2)&3)<<4) | (((x>>4)&3)<<2) | ((x>>6)&3);
}
__device__ __forceinline__ float2 cadd(float2 a, float2 b){ return make_float2(a.x+b.x, a.y+b.y); }
__device__ __forceinline__ float2 csub(float2 a, float2 b){ return make_float2(a.x-b.x, a.y-b.y); }
__device__ __forceinline__ float2 cmul(float2 a, float2 b){ return make_float2(a.x*b.x - a.y*b.y, a.x*b.y + a.y*b.x); }
__device__ __forceinline__ float2 cmulj(float2 a, float2 b){ return make_float2(a.x*b.x + a.y*b.y, a.y*b.x - a.x*b.y); }
__device__ __forceinline__ float2 addi(float2 a, float2 b){ return make_float2(a.x - b.y, a.y + b.x); }
__device__ __forceinline__ float2 subi(float2 a, float2 b){ return make_float2(a.x + b.y, a.y - b.x); }

#define LIDX(x) ((x) + ((x)>>2))
#define OUT_W(idx, val) do{ int _i = (idx); if ((unsigned)_i < (unsigned)osz) out[_i] = (val); }while(0)

// ---- forward mid stages q=32,8,2 (512-pt) ----
__device__ __forceinline__ void mid4f_512(float* re, float* im, int r){
  #pragma unroll
  for (int q = 32; q >= 2; q >>= 2){
    __syncthreads();
    int k = r & (q-1);
    int base = ((r - k) << 2) + k;
    int a0=LIDX(base), a1=LIDX(base+q), a2=LIDX(base+2*q), a3=LIDX(base+3*q);
    float x0r=re[a0], x0i=im[a0], x1r=re[a1], x1i=im[a1];
    float x2r=re[a2], x2i=im[a2], x3r=re[a3], x3i=im[a3];
    float t0r=x0r+x2r, t0i=x0i+x2i, t1r=x0r-x2r, t1i=x0i-x2i;
    float t2r=x1r+x3r, t2i=x1i+x3i, t3r=x1r-x3r, t3i=x1i-x3i;
    float y0r=t0r+t2r, y0i=t0i+t2i, y2r=t0r-t2r, y2i=t0i-t2i;
    float y1r=t1r+t3i, y1i=t1i-t3r;
    float y3r=t1r-t3i, y3i=t1i+t3r;
    float2 w1=g_tw[2*q+k], w2=g_tw[q+k];
    float w3r=w1.x*w2.x-w1.y*w2.y, w3i=w1.x*w2.y+w1.y*w2.x;
    re[a0]=y0r; im[a0]=y0i;
    re[a1]=y1r*w1.x-y1i*w1.y; im[a1]=y1r*w1.y+y1i*w1.x;
    re[a2]=y2r*w2.x-y2i*w2.y; im[a2]=y2r*w2.y+y2i*w2.x;
    re[a3]=y3r*w3r-y3i*w3i;  im[a3]=y3r*w3i+y3i*w3r;
  }
  __syncthreads();
}

// ---- inverse (DIT) mid stages q=2,8,32 ----
__device__ __forceinline__ void mid4i_512(float* re, float* im, int r){
  #pragma unroll
  for (int q = 2; q <= 32; q <<= 2){
    __syncthreads();
    int k = r & (q-1);
    int base = ((r - k) << 2) + k;
    int a0=LIDX(base), a1=LIDX(base+q), a2=LIDX(base+2*q), a3=LIDX(base+3*q);
    float z0r=re[a0], z0i=im[a0], z1r=re[a1], z1i=im[a1];
    float z2r=re[a2], z2i=im[a2], z3r=re[a3], z3i=im[a3];
    float2 w1=g_tw[2*q+k], w2=g_tw[q+k];
    float w3r=w1.x*w2.x-w1.y*w2.y, w3i=w1.x*w2.y+w1.y*w2.x;
    float b1r = z1r*w1.x + z1i*w1.y, b1i = z1i*w1.x - z1r*w1.y;
    float b2r = z2r*w2.x + z2i*w2.y, b2i = z2i*w2.x - z2r*w2.y;
    float b3r = z3r*w3r + z3i*w3i,  b3i = z3i*w3r - z3r*w3i;
    float u0r=z0r+b2r, u0i=z0i+b2i, u1r=z0r-b2r, u1i=z0i-b2i;
    float u2r=b1r+b3r, u2i=b1i+b3i, u3r=b1r-b3r, u3i=b1i-b3i;
    re[a0]=u0r+u2r; im[a0]=u0i+u2i;
    re[a1]=u1r-u3i; im[a1]=u1i+u3r;
    re[a2]=u0r-u2r; im[a2]=u0i-u2i;
    re[a3]=u1r+u3i; im[a3]=u1i-u3r;
  }
  __syncthreads();
}

// ================= L1: init (tw + separable PE@W1 tables) + norm1 =================
__global__ __launch_bounds__(256, 3) void k_L1(const float* __restrict__ gw0,
                                            const float* __restrict__ gb0,
                                            const float* __restrict__ gw1,
                                            const float* __restrict__ gb1,
                                            const float* __restrict__ x){
  int bid = blockIdx.x;
  if (bid < 66){
    int t = bid*256 + threadIdx.x;
    if (t < 512){
      if (t == 0){ g_tw[0] = make_float2(1.f, 0.f); return; }
      int h = 1 << (31 - __clz(t));
      int k = t - h;
      double a = -M_PI * (double)k / (double)h;
      g_tw[t] = make_float2((float)cos(a), (float)sin(a));
      return;
    }
    int t2 = t - 512;
    if (t2 >= 16384) return;
    int isG = t2 >> 13;
    int pos = (t2 >> 5) & 255;
    int j = t2 & 31;
    float xx = (float)(-1.0 + (2.0 * pos) / 255.0);
    float s1, c1; sincosf(xx, &s1, &c1);
    float s = s1, c = c1;
    float acc = 0.f;
    if (!isG){
      acc = gb1[j];
      #pragma unroll
      for (int k = 0; k < 32; k++) acc += gb0[k]*gw1[k*32 + j];
    }
    #pragma unroll
    for (int i = 1; i <= 15; i++){
      const float* rs = gw0 + (4*(i-1) + isG)*32;
      const float* rc = gw0 + (4*(i-1) + 2 + isG)*32;
      float Ms = 0.f, Mc = 0.f;
      #pragma unroll
      for (int k = 0; k < 32; k++){
        float wc = gw1[k*32 + j];
        Ms += rs[k]*wc; Mc += rc[k]*wc;
      }
      acc += s*Ms + c*Mc;
      float ns = s*c1 + c*s1, nc = c*c1 - s*s1;
      s = ns; c = nc;
    }
    if (isG) g_GW1[pos*32 + j] = acc;
    else     g_FW1[pos*32 + j] = acc;
  } else {
    int b = bid - 66;
    int tid = threadIdx.x;
    float4 v = ((const float4*)x)[(size_t)b*256 + tid];
    float s = v.x*v.x + v.y*v.y + v.z*v.z + v.w*v.w;
    __shared__ float red[256];
    red[tid] = s; __syncthreads();
    for (int w = 128; w > 0; w >>= 1){ if (tid < w) red[tid] += red[tid+w]; __syncthreads(); }
    if (tid == 0) g_partial[b] = red[0];
  }
}

// ================= L2: gmlp + patch + norm2 — 2 px/thread, capped VGPR =================
__device__ __forceinline__ void gmlp_body(int bid, float* sw, float* hb,
    const float* __restrict__ gw2,
    const float* __restrict__ l1w, const float* __restrict__ l1b,
    const float* __restrict__ gb2, const float* __restrict__ l2w, const float* __restrict__ l2b,
    const float* __restrict__ gw3, const float* __restrict__ gb3)
{
  int tid = threadIdx.x;
  #pragma unroll
  for (int i = 0; i < 4; i++) sw[tid + 256*i] = gw2[tid + 256*i];
  __syncthreads();

  int waveid = tid >> 6, lane = tid & 63;
  int group = lane >> 3, j8 = lane & 7;
  int gidx = tid >> 3;
  int p0 = bid*64 + waveid*16 + group*2;
  int cb = 4*j8;

  float4 lw1 = *(const float4*)&l1w[cb];
  float4 lb1 = *(const float4*)&l1b[cb];
  #pragma unroll
  for (int u = 0; u < 2; u++){
    int p = p0 + u;
    int r = p >> 8, c = p & 255;
    float4 A4 = *(const float4*)&g_FW1[c*32 + cb];
    float4 B4 = *(const float4*)&g_GW1[r*32 + cb];
    float h0 = A4.x+B4.x, h1v = A4.y+B4.y, h2v = A4.z+B4.z, h3 = A4.w+B4.w;
    float s = h0+h1v+h2v+h3;
    s += __shfl_xor(s,1,8); s += __shfl_xor(s,2,8); s += __shfl_xor(s,4,8);
    float mean = s*(1.0f/32.0f);
    float d0=h0-mean, d1=h1v-mean, d2=h2v-mean, d3=h3-mean;
    float vv = d0*d0+d1*d1+d2*d2+d3*d3;
    vv += __shfl_xor(vv,1,8); vv += __shfl_xor(vv,2,8); vv += __shfl_xor(vv,4,8);
    float inv = rsqrtf(vv*(1.0f/32.0f) + 1e-5f);
    float t0=d0*inv*lw1.x+lb1.x, t1=d1*inv*lw1.y+lb1.y, t2=d2*inv*lw1.z+lb1.z, t3=d3*inv*lw1.w+lb1.w;
    t0 = (t0>0.f)?t0:0.01f*t0; t1 = (t1>0.f)?t1:0.01f*t1;
    t2 = (t2>0.f)?t2:0.01f*t2; t3 = (t3>0.f)?t3:0.01f*t3;
    hb[(u*32 + cb + 0)*33 + gidx] = t0;
    hb[(u*32 + cb + 1)*33 + gidx] = t1;
    hb[(u*32 + cb + 2)*33 + gidx] = t2;
    hb[(u*32 + cb + 3)*33 + gidx] = t3;
  }

  float4 b2v = *(const float4*)&gb2[cb];
  float h2[2][4];
  #pragma unroll
  for (int u=0;u<2;u++){ h2[u][0]=b2v.x; h2[u][1]=b2v.y; h2[u][2]=b2v.z; h2[u][3]=b2v.w; }
  #pragma unroll
  for (int k = 0; k < 32; k++){
    float4 w = *(const float4*)&sw[k*32 + cb];
    float a0 = hb[(0*32+k)*33 + gidx];
    float a1 = hb[(1*32+k)*33 + gidx];
    h2[0][0]+=a0*w.x; h2[0][1]+=a0*w.y; h2[0][2]+=a0*w.z; h2[0][3]+=a0*w.w;
    h2[1][0]+=a1*w.x; h2[1][1]+=a1*w.y; h2[1][2]+=a1*w.z; h2[1][3]+=a1*w.w;
  }
  {
    float4 lw = *(const float4*)&l2w[cb];
    float4 lb = *(const float4*)&l2b[cb];
    #pragma unroll
    for (int u=0;u<2;u++){
      float s = h2[u][0]+h2[u][1]+h2[u][2]+h2[u][3];
      s += __shfl_xor(s,1,8); s += __shfl_xor(s,2,8); s += __shfl_xor(s,4,8);
      float mean = s*(1.0f/32.0f);
      float d0=h2[u][0]-mean, d1=h2[u][1]-mean, d2=h2[u][2]-mean, d3=h2[u][3]-mean;
      float vv = d0*d0+d1*d1+d2*d2+d3*d3;
      vv += __shfl_xor(vv,1,8); vv += __shfl_xor(vv,2,8); vv += __shfl_xor(vv,4,8);
      float inv = rsqrtf(vv*(1.0f/32.0f) + 1e-5f);
      float t0=d0*inv*lw.x+lb.x, t1=d1*inv*lw.y+lb.y, t2=d2*inv*lw.z+lb.z, t3=d3*inv*lw.w+lb.w;
      h2[u][0] = (t0>0.f)?t0:0.01f*t0; h2[u][1] = (t1>0.f)?t1:0.01f*t1;
      h2[u][2] = (t2>0.f)?t2:0.01f*t2; h2[u][3] = (t3>0.f)?t3:0.01f*t3;
    }
  }

  float4 w3v = *(const float4*)&gw3[cb];
  float b3 = gb3[0];
  #pragma unroll
  for (int u=0;u<2;u++){
    float pp = h2[u][0]*w3v.x + h2[u][1]*w3v.y + h2[u][2]*w3v.z + h2[u][3]*w3v.w;
    pp += __shfl_xor(pp,1,8); pp += __shfl_xor(pp,2,8); pp += __shfl_xor(pp,4,8);
    float phs = pp + b3;
    if (j8 == 0){
      float sp, cp; sincosf(phs, &sp, &cp);
      g_phs[p0+u] = phs;
      g_cs[p0+u] = make_float2(cp, sp);
    }
  }
}

__device__ __forceinline__ void patch_body(int bid, float* sw, float* hb,
    const float* __restrict__ pdata, const float* __restrict__ rw0, const float* __restrict__ rb0,
    const float* __restrict__ rw1, const float* __restrict__ rb1,
    const float* __restrict__ rw2, const float* __restrict__ rb2,
    float* out, int osz, int offIest)
{
  int tid = threadIdx.x;
  int p0 = bid*64 + (tid >> 6)*16 + ((tid & 63) >> 3)*2;
  int patch = p0 >> 14;

  const float* w0g = rw0 + patch*1024;
  const float* w1g = rw1 + patch*1024;
  #pragma unroll
  for (int i = 0; i < 4; i++){
    sw[tid + 256*i] = w0g[tid + 256*i];
    sw[1024 + tid + 256*i] = w1g[tid + 256*i];
  }
  __syncthreads();

  int lane = tid & 63;
  int j8 = lane & 7;
  int gidx = tid >> 3;
  int pl0 = p0 & 16383;
  int i = pl0 >> 7, jp = pl0 & 127;
  int i1 = min(i+1, 127);
  int cb = 4*j8;

  const float* base = pdata + (size_t)patch * 128*128*32;
  #pragma unroll
  for (int u = 0; u < 2; u++){
    int j = jp + u, j1 = min(j+1, 127);
    float4 a  = *(const float4*)&base[(i *128 + j )*32 + cb];
    float4 b  = *(const float4*)&base[(i *128 + j1)*32 + cb];
    float4 cc = *(const float4*)&base[(i1*128 + j )*32 + cb];
    float4 d  = *(const float4*)&base[(i1*128 + j1)*32 + cb];
    hb[(u*32 + cb + 0)*33 + gidx] = 0.25f*(a.x+b.x+cc.x+d.x);
    hb[(u*32 + cb + 1)*33 + gidx] = 0.25f*(a.y+b.y+cc.y+d.y);
    hb[(u*32 + cb + 2)*33 + gidx] = 0.25f*(a.z+b.z+cc.z+d.z);
    hb[(u*32 + cb + 3)*33 + gidx] = 0.25f*(a.w+b.w+cc.w+d.w);
  }

  float4 b0v = *(const float4*)&rb0[patch*32 + cb];
  float h[2][4];
  #pragma unroll
  for (int u=0;u<2;u++){ h[u][0]=b0v.x; h[u][1]=b0v.y; h[u][2]=b0v.z; h[u][3]=b0v.w; }
  #pragma unroll
  for (int k = 0; k < 32; k++){
    float4 w = *(const float4*)&sw[k*32 + cb];
    float a0 = hb[(0*32+k)*33 + gidx];
    float a1 = hb[(1*32+k)*33 + gidx];
    h[0][0]+=a0*w.x; h[0][1]+=a0*w.y; h[0][2]+=a0*w.z; h[0][3]+=a0*w.w;
    h[1][0]+=a1*w.x; h[1][1]+=a1*w.y; h[1][2]+=a1*w.z; h[1][3]+=a1*w.w;
  }
  #pragma unroll
  for (int u=0;u<2;u++){
    hb[(u*32 + cb + 0)*33 + gidx] = fmaxf(h[u][0],0.f);
    hb[(u*32 + cb + 1)*33 + gidx] = fmaxf(h[u][1],0.f);
    hb[(u*32 + cb + 2)*33 + gidx] = fmaxf(h[u][2],0.f);
    hb[(u*32 + cb + 3)*33 + gidx] = fmaxf(h[u][3],0.f);
  }

  float4 b1v = *(const float4*)&rb1[patch*32 + cb];
  float g[2][4];
  #pragma unroll
  for (int u=0;u<2;u++){ g[u][0]=b1v.x; g[u][1]=b1v.y; g[u][2]=b1v.z; g[u][3]=b1v.w; }
  #pragma unroll
  for (int k = 0; k < 32; k++){
    float4 w = *(const float4*)&sw[1024 + k*32 + cb];
    float a0 = hb[(0*32+k)*33 + gidx];
    float a1 = hb[(1*32+k)*33 + gidx];
    g[0][0]+=a0*w.x; g[0][1]+=a0*w.y; g[0][2]+=a0*w.z; g[0][3]+=a0*w.w;
    g[1][0]+=a1*w.x; g[1][1]+=a1*w.y; g[1][2]+=a1*w.z; g[1][3]+=a1*w.w;
  }

  float4 w2v = *(const float4*)&rw2[patch*32 + cb];
  float b2s = rb2[patch];
  #pragma unroll
  for (int u=0;u<2;u++){
    float o = fmaxf(g[u][0],0.f)*w2v.x + fmaxf(g[u][1],0.f)*w2v.y
            + fmaxf(g[u][2],0.f)*w2v.z + fmaxf(g[u][3],0.f)*w2v.w;
    o += __shfl_xor(o,1,8); o += __shfl_xor(o,2,8); o += __shfl_xor(o,4,8);
    o += b2s;
    if (j8 == 0){
      int pr = (patch >> 1)*128 + i;
      int pc = (patch & 1)*128 + jp + u;
      g_I[pr*256 + pc] = o;
      OUT_W(offIest + pr*256 + pc, o);
    }
  }
}

__device__ __forceinline__ void norm2_body(){
  int tid = threadIdx.x;
  int b = tid >> 4, l = tid & 15;
  float s = 0.f;
  #pragma unroll
  for (int j = 0; j < 4; j++) s += g_partial[b*64 + l + 16*j];
  #pragma unroll
  for (int d = 8; d > 0; d >>= 1) s += __shfl_down(s, d, 16);
  if (l == 0) g_norms[b] = 65536.0f * s;
}

__global__ __launch_bounds__(256, 4) void k_L2(
    const float* __restrict__ gw2,
    const float* __restrict__ l1w, const float* __restrict__ l1b,
    const float* __restrict__ gb2, const float* __restrict__ l2w, const float* __restrict__ l2b,
    const float* __restrict__ gw3, const float* __restrict__ gb3,
    const float* __restrict__ pdata, const float* __restrict__ rw0, const float* __restrict__ rb0,
    const float* __restrict__ rw1, const float* __restrict__ rb1,
    const float* __restrict__ rw2, const float* __restrict__ rb2,
    float* out, int osz, int offIest)
{
  __shared__ float sw[2048];
  __shared__ float hb[2112];   // 64*33 floats
  int bid = blockIdx.x;
  if (bid < 1024)      gmlp_body(bid, sw, hb, gw2, l1w, l1b, gb2, l2w, l2b, gw3, gb3);
  else if (bid < 2048) patch_body(bid-1024, sw, hb, pdata, rw0, rb0, rw1, rb1, rw2, rb2, out, osz, offIest);
  else                 norm2_body();
}

// ================= L3: S_row + field_row + bcast =================
__device__ __forceinline__ void srow_body(int bid, float* sm){
  int t = threadIdx.x;
  int row = t >> 7, r = t & 127;
  int gr = bid*2 + row;
  float* rre = sm + row*640; float* rim = sm + 1280 + row*640;
  float A = g_I[gr*256 + r], B = g_I[gr*256 + r + 128];
  {
    float2 w1 = g_tw[256+r], w2 = g_tw[128+r];
    float w3r = w1.x*w2.x - w1.y*w2.y, w3i = w1.x*w2.y + w1.y*w2.x;
    float s = A + B, d = A - B;
    rre[LIDX(r)]     = s;                   rim[LIDX(r)]     = 0.f;
    rre[LIDX(r+128)] = A*w1.x + B*w1.y;     rim[LIDX(r+128)] = A*w1.y - B*w1.x;
    rre[LIDX(r+256)] = d*w2.x;              rim[LIDX(r+256)] = d*w2.y;
    rre[LIDX(r+384)] = A*w3r - B*w3i;       rim[LIDX(r+384)] = A*w3i + B*w3r;
  }
  mid4f_512(rre, rim, r);
  float2* Srow = &g_SfA[gr*512];
  #pragma unroll
  for (int h = 0; h < 2; h++){
    int g = r + 128*h;
    int a0 = LIDX(2*g), a1 = LIDX(2*g+1);
    float ar = rre[a0], ai = rim[a0], br = rre[a1], bi = rim[a1];
    *(float4*)&Srow[2*g] = make_float4(ar+br, ai+bi, ar-br, ai-bi);
  }
}

__device__ __forceinline__ void frow_body(int bid, const float* __restrict__ x, float* sm){
  int t = threadIdx.x;
  int row = t >> 6, l = t & 63;
  int gr = bid*4 + row;
  int b = gr >> 8, xr = gr & 255;
  float* rre = sm + row*320; float* rim = sm + 1280 + row*320;
  const float* xrow = x + ((size_t)b*256 + xr)*256;
  const float2* csrow = g_cs + xr*256;

  float x0r,x0i,x1r,x1i,x2r,x2i,x3r,x3i;
  { float xv=xrow[l];      float2 cs=csrow[l];      x0r=xv*cs.x; x0i=xv*cs.y; }
  { float xv=xrow[l+64];   float2 cs=csrow[l+64];   x1r=xv*cs.x; x1i=xv*cs.y; }
  { float xv=xrow[l+128];  float2 cs=csrow[l+128];  x2r=xv*cs.x; x2i=xv*cs.y; }
  { float xv=xrow[l+192];  float2 cs=csrow[l+192];  x3r=xv*cs.x; x3i=xv*cs.y; }
  {
    float t0r=x0r+x2r, t0i=x0i+x2i, t1r=x0r-x2r, t1i=x0i-x2i;
    float t2r=x1r+x3r, t2i=x1i+x3i, t3r=x1r-x3r, t3i=x1i-x3i;
    float y0r=t0r+t2r, y0i=t0i+t2i, y2r=t0r-t2r, y2i=t0i-t2i;
    float y1r=t1r+t3i, y1i=t1i-t3r;
    float y3r=t1r-t3i, y3i=t1i+t3r;
    float2 w1=g_tw[128+l], w2=g_tw[64+l];
    float w3r=w1.x*w2.x-w1.y*w2.y, w3i=w1.x*w2.y+w1.y*w2.x;
    rre[LIDX(l)]     = y0r;                     rim[LIDX(l)]     = y0i;
    rre[LIDX(l+64)]  = y1r*w1.x-y1i*w1.y;       rim[LIDX(l+64)]  = y1r*w1.y+y1i*w1.x;
    rre[LIDX(l+128)] = y2r*w2.x-y2i*w2.y;       rim[LIDX(l+128)] = y2r*w2.y+y2i*w2.x;
    rre[LIDX(l+192)] = y3r*w3r-y3i*w3i;         rim[LIDX(l+192)] = y3r*w3i+y3i*w3r;
  }
  #pragma unroll
  for (int q = 16; q >= 4; q >>= 2){
    __syncthreads();
    int k = l & (q-1);
    int base = ((l - k) << 2) + k;
    int a0=LIDX(base), a1=LIDX(base+q), a2=LIDX(base+2*q), a3=LIDX(base+3*q);
    float z0r=rre[a0], z0i=rim[a0], z1r=rre[a1], z1i=rim[a1];
    float z2r=rre[a2], z2i=rim[a2], z3r=rre[a3], z3i=rim[a3];
    float t0r=z0r+z2r, t0i=z0i+z2i, t1r=z0r-z2r, t1i=z0i-z2i;
    float t2r=z1r+z3r, t2i=z1i+z3i, t3r=z1r-z3r, t3i=z1i-z3i;
    float y0r=t0r+t2r, y0i=t0i+t2i, y2r=t0r-t2r, y2i=t0i-t2i;
    float y1r=t1r+t3i, y1i=t1i-t3r;
    float y3r=t1r-t3i, y3i=t1i+t3r;
    float2 w1=g_tw[2*q+k], w2=g_tw[q+k];
    float w3r=w1.x*w2.x-w1.y*w2.y, w3i=w1.x*w2.y+w1.y*w2.x;
    rre[a0]=y0r; rim[a0]=y0i;
    rre[a1]=y1r*w1.x-y1i*w1.y; rim[a1]=y1r*w1.y+y1i*w1.x;
    rre[a2]=y2r*w2.x-y2i*w2.y; rim[a2]=y2r*w2.y+y2i*w2.x;
    rre[a3]=y3r*w3r-y3i*w3i;  rim[a3]=y3r*w3i+y3i*w3r;
  }
  __syncthreads();
  {
    int a0=LIDX(4*l), a1=LIDX(4*l+1), a2=LIDX(4*l+2), a3=LIDX(4*l+3);
    float z0r=rre[a0], z0i=rim[a0], z1r=rre[a1], z1i=rim[a1];
    float z2r=rre[a2], z2i=rim[a2], z3r=rre[a3], z3i=rim[a3];
    float t0r=z0r+z2r, t0i=z0i+z2i, t1r=z0r-z2r, t1i=z0i-z2i;
    float t2r=z1r+z3r, t2i=z1i+z3i, t3r=z1r-z3r, t3i=z1i-z3i;
    float2* Frow = &g_F[((size_t)b*256 + xr)*256];
    Frow[rev4d8(4*l)]   = make_float2(t0r+t2r, t0i+t2i);
    Frow[rev4d8(4*l+1)] = make_float2(t1r+t3i, t1i-t3r);
    Frow[rev4d8(4*l+2)] = make_float2(t0r-t2r, t0i-t2i);
    Frow[rev4d8(4*l+3)] = make_float2(t1r-t3i, t1i+t3r);
  }
}

__device__ __forceinline__ void bcast_body(int bid, float* out, int osz, int offG, int offPhs, int interleaved){
  int idx = bid*256 + threadIdx.x;
  int p = idx & 65535, b = idx >> 16;
  float phs = g_phs[p];
  float2 cs = g_cs[p];
  OUT_W(offPhs + b*65536 + p, phs);
  if (interleaved){
    int gi = offG + 2*(b*65536 + p);
    if (gi + 1 < osz) *(float2*)(out + gi) = cs;
  } else {
    OUT_W(offG + b*65536 + p, cs.x);
  }
}

__global__ __launch_bounds__(256) void k_L3(const float* __restrict__ x, float* out, int osz,
                                            int offG, int offPhs, int interleaved){
  __shared__ float sm[2560];
  int bid = blockIdx.x;
  if (bid < 128)       srow_body(bid, sm);
  else if (bid < 1152) frow_body(bid-128, x, sm);
  else                 bcast_body(bid-1152, out, osz, offG, offPhs, interleaved);
}

// ================= L4: S_col + field_col(+mag->d_out) =================
__device__ __forceinline__ void fold512_load(const float2* src, float2* buf, int c, int rr){
  for (int i = rr; i < 128; i += 32){
    float2 a = src[(size_t)i*512];
    float2 b = src[(size_t)(i+128)*512];
    float2 w1 = g_tw[256+i], w2 = g_tw[128+i];
    float2 w3 = cmul(w1, w2);
    buf[i*9+c]       = cadd(a,b);
    buf[(i+128)*9+c] = cmul(subi(a,b), w1);
    buf[(i+256)*9+c] = cmul(csub(a,b), w2);
    buf[(i+384)*9+c] = cmul(addi(a,b), w3);
  }
}

__device__ __forceinline__ void dif4_stages_512(float2* buf, int c, int rr){
  #pragma unroll
  for (int q = 32; q >= 2; q >>= 2){
    __syncthreads();
    for (int g = rr; g < 128; g += 32){
      int k = g & (q-1);
      int base = ((g - k) << 2) + k;
      float2 x0 = buf[base*9+c], x1 = buf[(base+q)*9+c];
      float2 x2 = buf[(base+2*q)*9+c], x3 = buf[(base+3*q)*9+c];
      float2 t0=cadd(x0,x2), t1=csub(x0,x2), t2=cadd(x1,x3), t3=csub(x1,x3);
      float2 y0=cadd(t0,t2), y1=subi(t1,t3), y2=csub(t0,t2), y3=addi(t1,t3);
      float2 w1 = g_tw[2*q+k], w2 = g_tw[q+k];
      float2 w3 = cmul(w1,w2);
      buf[base*9+c]       = y0;
      buf[(base+q)*9+c]   = cmul(y1,w1);
      buf[(base+2*q)*9+c] = cmul(y2,w2);
      buf[(base+3*q)*9+c] = cmul(y3,w3);
    }
  }
}

__device__ __forceinline__ void scol_body(int bid, float2* buf){
  int v0 = bid << 3;
  int tid = threadIdx.x, c = tid & 7, rr = tid >> 3;
  int v = v0 + c;
  fold512_load(&g_SfA[v], buf, c, rr);
  dif4_stages_512(buf, c, rr);
  __syncthreads();
  for (int g = rr; g < 256; g += 32){
    int i0 = 2*g;
    float2 a = buf[i0*9+c], b = buf[(i0+1)*9+c];
    g_Sf[(size_t)i0*512 + v]     = cadd(a,b);
    g_Sf[(size_t)(i0+1)*512 + v] = csub(a,b);
  }
}

__device__ __forceinline__ void fcol_body(int bid, float2* buf, float* out, int osz, int offKer){
  int b = bid >> 5, v0 = (bid & 31) << 3;
  int tid = threadIdx.x, c = tid & 7, rr = tid >> 3;
  const float2* Fr = &g_F[(size_t)b*65536 + v0 + c];
  for (int r = rr; r < 256; r += 32) buf[r*9+c] = Fr[(size_t)r*256];
  #pragma unroll
  for (int q = 64; q >= 1; q >>= 2){
    __syncthreads();
    for (int g = rr; g < 64; g += 32){
      int k = g & (q-1);
      int base = ((g - k) << 2) + k;
      float2 x0 = buf[base*9+c], x1 = buf[(base+q)*9+c];
      float2 x2 = buf[(base+2*q)*9+c], x3 = buf[(base+3*q)*9+c];
      float2 t0=cadd(x0,x2), t1=csub(x0,x2), t2=cadd(x1,x3), t3=csub(x1,x3);
      float2 y0=cadd(t0,t2), y1=subi(t1,t3), y2=csub(t0,t2), y3=addi(t1,t3);
      if (q > 1){
        float2 w1 = g_tw[2*q+k], w2 = g_tw[q+k];
        float2 w3 = cmul(w1,w2);
        y1 = cmul(y1,w1); y2 = cmul(y2,w2); y3 = cmul(y3,w3);
      }
      buf[base*9+c]=y0; buf[(base+q)*9+c]=y1; buf[(base+2*q)*9+c]=y2; buf[(base+3*q)*9+c]=y3;
    }
  }
  __syncthreads();
  float invn = 1.0f / g_norms[b];
  int v = v0 + c;
  int e = (127 - v) & 255;
  for (int p = rr; p < 256; p += 32){
    float2 f = buf[p*9+c];
    int a = rev4d8(p);
    int rt = (127 - a) & 255;
    float kv = (f.x*f.x + f.y*f.y) * invn;
    OUT_W(offKer + b*65536 + rt*256 + e, kv);
  }
}

__global__ __launch_bounds__(256) void k_L4(float* out, int osz, int offKer){
  __shared__ float2 buf[512*9];
  int bid = blockIdx.x;
  if (bid < 64) scol_body(bid, buf);
  else          fcol_body(bid-64, buf, out, osz, offKer);
}

// ============ L5: packed kernel-row FFT (reads kernel from d_out) ============
__global__ __launch_bounds__(256) void k_krow(const float* __restrict__ out_ro, int osz, int offKer){
  __shared__ float re[2*640], im[2*640];
  int t = threadIdx.x;
  int row = t >> 7, r = t & 127;
  int gr = blockIdx.x*2 + row;
  int q = gr >> 8, kr = gr & 255;
  int b0 = 2*q, b1 = 2*q + 1;
  float* rre = re + row*640; float* rim = im + row*640;

  const float* k0 = out_ro + offKer + b0*65536 + kr*256;
  const float* k1 = out_ro + offKer + b1*65536 + kr*256;
  float2 zA = make_float2(k0[r],      k1[r]);
  float2 zB = make_float2(k0[r+128],  k1[r+128]);

  {
    float2 w1 = g_tw[256+r], w2 = g_tw[128+r];
    float2 w3 = cmul(w1, w2);
    float2 p0 = cadd(zA, zB);
    float2 p1 = cmul(subi(zA, zB), w1);
    float2 p2 = cmul(csub(zA, zB), w2);
    float2 p3 = cmul(addi(zA, zB), w3);
    rre[LIDX(r)]     = p0.x; rim[LIDX(r)]     = p0.y;
    rre[LIDX(r+128)] = p1.x; rim[LIDX(r+128)] = p1.y;
    rre[LIDX(r+256)] = p2.x; rim[LIDX(r+256)] = p2.y;
    rre[LIDX(r+384)] = p3.x; rim[LIDX(r+384)] = p3.y;
  }
  mid4f_512(rre, rim, r);
  float2* KArow = &g_KA[((size_t)q*256 + kr)*512];
  #pragma unroll
  for (int h = 0; h < 2; h++){
    int g = r + 128*h;
    int a0 = LIDX(2*g), a1 = LIDX(2*g+1);
    float ar = rre[a0], ai = rim[a0], br = rre[a1], bi = rim[a1];
    *(float4*)&KArow[2*g] = make_float4(ar+br, ai+bi, ar-br, ai-bi);
  }
}

// ============ L6: fused col pass (8 packed images) ============
__global__ __launch_bounds__(256) void k_col_mul_inv(){
  __shared__ float2 buf[512*9];
  int bi = blockIdx.x >> 6, v0 = (blockIdx.x & 63) << 3;
  int tid = threadIdx.x, c = tid & 7, rr = tid >> 3;
  int v = v0 + c;

  fold512_load(&g_KA[((size_t)bi*256)*512 + v], buf, c, rr);
  dif4_stages_512(buf, c, rr);

  __syncthreads();
  for (int g = rr; g < 256; g += 32){
    int i0 = 2*g;
    float2 a = buf[i0*9+c], b = buf[(i0+1)*9+c];
    float2 y0 = cadd(a,b), y1 = csub(a,b);
    float2 s0 = g_Sf[(size_t)i0*512 + v];
    float2 s1 = g_Sf[(size_t)(i0+1)*512 + v];
    float2 z0 = cmul(y0,s0), z1 = cmul(y1,s1);
    buf[i0*9+c]     = cadd(z0,z1);
    buf[(i0+1)*9+c] = csub(z0,z1);
  }

  #pragma unroll
  for (int q = 2; q <= 32; q <<= 2){
    __syncthreads();
    for (int g = rr; g < 128; g += 32){
      int k = g & (q-1);
      int base = ((g - k) << 2) + k;
      float2 z0 = buf[base*9+c], z1 = buf[(base+q)*9+c];
      float2 z2 = buf[(base+2*q)*9+c], z3 = buf[(base+3*q)*9+c];
      float2 w1 = g_tw[2*q+k], w2 = g_tw[q+k];
      float2 w3 = cmul(w1,w2);
      z1 = cmulj(z1,w1); z2 = cmulj(z2,w2); z3 = cmulj(z3,w3);
      float2 u0=cadd(z0,z2), u1=csub(z0,z2), u2=cadd(z1,z3), u3=csub(z1,z3);
      buf[base*9+c]       = cadd(u0,u2);
      buf[(base+q)*9+c]   = addi(u1,u3);
      buf[(base+2*q)*9+c] = csub(u0,u2);
      buf[(base+3*q)*9+c] = subi(u1,u3);
    }
  }

  __syncthreads();
  for (int i = rr; i < 128; i += 32){
    float2 z0 = buf[i*9+c], z1 = buf[(i+128)*9+c];
    float2 z2 = buf[(i+256)*9+c], z3 = buf[(i+384)*9+c];
    float2 w1 = g_tw[256+i], w2 = g_tw[128+i];
    float2 w3 = cmul(w1,w2);
    z1 = cmulj(z1,w1); z2 = cmulj(z2,w2); z3 = cmulj(z3,w3);
    float2 u0=cadd(z0,z2), u1=csub(z0,z2), u2=cadd(z1,z3), u3=csub(z1,z3);
    g_P[((size_t)bi*256 + i)*512 + v]       = addi(u1,u3);
    g_P[((size_t)bi*256 + i + 128)*512 + v] = csub(u0,u2);
  }
}

// ============ L7: packed inverse row FFT; Re->batch 2q, Im->batch 2q+1 ============
__global__ __launch_bounds__(256) void k_ifft_row(float* out, int osz){
  __shared__ float re[2*640], im[2*640];
  int t = threadIdx.x;
  int row = t >> 7, r = t & 127;
  int gr = blockIdx.x*2 + row;
  int q = gr >> 8, ri = gr & 255;
  int b0 = 2*q, b1 = 2*q + 1;
  float* rre = re + row*640; float* rim = im + row*640;
  const float2* Prow = &g_P[((size_t)q*256 + ri)*512];

  #pragma unroll
  for (int h = 0; h < 2; h++){
    int g = r + 128*h;
    float4 pq = *(const float4*)&Prow[2*g];
    rre[LIDX(2*g)]   = pq.x + pq.z;  rim[LIDX(2*g)]   = pq.y + pq.w;
    rre[LIDX(2*g+1)] = pq.x - pq.z;  rim[LIDX(2*g+1)] = pq.y - pq.w;
  }
  mid4i_512(rre, rim, r);
  {
    int a0=LIDX(r), a1=LIDX(r+128), a2=LIDX(r+256), a3=LIDX(r+384);
    float z0r=rre[a0], z0i=rim[a0];
    float z1r=rre[a1], z1i=rim[a1];
    float z2r=rre[a2], z2i=rim[a2];
    float z3r=rre[a3], z3i=rim[a3];
    float2 w1 = g_tw[256+r], w2 = g_tw[128+r];
    float w3r=w1.x*w2.x-w1.y*w2.y, w3i=w1.x*w2.y+w1.y*w2.x;
    float b1r = z1r*w1.x + z1i*w1.y, b1i = z1i*w1.x - z1r*w1.y;
    float b2r = z2r*w2.x + z2i*w2.y, b2i = z2i*w2.x - z2r*w2.y;
    float b3r = z3r*w3r + z3i*w3i,  b3i = z3i*w3r - z3r*w3i;
    float u0r = z0r + b2r, u0i = z0i + b2i;
    float u1r = z0r - b2r, u1i = z0i - b2i;
    float u2r = b1r + b3r, u2i = b1i + b3i;
    float u3r = b1r - b3r, u3i = b1i - b3i;
    const float sc = 1.0f / 262144.0f;
    OUT_W(b0*65536 + ri*256 + r,       (u1r - u3i) * sc);
    OUT_W(b1*65536 + ri*256 + r,       (u1i + u3r) * sc);
    OUT_W(b0*65536 + ri*256 + r + 128, (u0r - u2r) * sc);
    OUT_W(b1*65536 + ri*256 + r + 128, (u0i - u2i) * sc);
  }
}

extern "C" void kernel_launch(void* const* d_in, const int* in_sizes, int n_in,
                              void* d_out, int out_size, void* d_ws, size_t ws_size,
                              hipStream_t stream) {
  static const int expect[21] = {
    16*65536, 16, 4*128*128*32,
    4*32*32, 4*32, 4*32*32, 4*32, 4*32, 4,
    60*32, 32, 32*32, 32, 32, 32, 32*32, 32, 32, 32, 32, 1
  };
  if (n_in < 21) return;
  for (int i = 0; i < 21; i++) if (in_sizes[i] != expect[i]) return;

  const float* x_batch = (const float*)d_in[0];
  const float* pdata = (const float*)d_in[2];
  const float* rw0 = (const float*)d_in[3];
  const float* rb0 = (const float*)d_in[4];
  const float* rw1 = (const float*)d_in[5];
  const float* rb1 = (const float*)d_in[6];
  const float* rw2 = (const float*)d_in[7];
  const float* rb2 = (const float*)d_in[8];
  const float* gw0 = (const float*)d_in[9];
  const float* gb0 = (const float*)d_in[10];
  const float* gw1 = (const float*)d_in[11];
  const float* gb1 = (const float*)d_in[12];
  const float* l1w = (const float*)d_in[13];
  const float* l1b = (const float*)d_in[14];
  const float* gw2 = (const float*)d_in[15];
  const float* gb2 = (const float*)d_in[16];
  const float* l2w = (const float*)d_in[17];
  const float* l2b = (const float*)d_in[18];
  const float* gw3 = (const float*)d_in[19];
  const float* gb3 = (const float*)d_in[20];

  float* out = (float*)d_out;

  int interleaved = (out_size >= 5308416) ? 1 : 0;
  int offKer  = 1048576;
  int offG    = 2097152;
  int offPhs  = interleaved ? 4194304 : 3145728;
  int offIest = interleaved ? 5242880 : 4194304;

  k_L1<<<1090, 256, 0, stream>>>(gw0, gb0, gw1, gb1, x_batch);
  k_L2<<<2049, 256, 0, stream>>>(gw2, l1w, l1b, gb2, l2w, l2b, gw3, gb3,
                                 pdata, rw0, rb0, rw1, rb1, rw2, rb2, out, out_size, offIest);
  k_L3<<<5248, 256, 0, stream>>>(x_batch, out, out_size, offG, offPhs, interleaved);
  k_L4<<<576, 256, 0, stream>>>(out, out_size, offKer);
  k_krow<<<1024, 256, 0, stream>>>(out, out_size, offKer);
  k_col_mul_inv<<<512, 256, 0, stream>>>();
  k_ifft_row<<<1024, 256, 0, stream>>>(out, out_size);
}

// Round 20
// 73.148 us; speedup vs baseline: 1.2298x; 1.2298x over previous
//
#include <hip/hip_runtime.h>
#include <math.h>

// ---- all scratch as device globals ----
__device__ float  g_norms[16];
__device__ float  g_partial[1024];
__device__ float  g_phs[65536];
__device__ float2 g_cs[65536];
__device__ float  g_Fx[256*32];
__device__ float  g_Gy[256*32];
__device__ float  g_I[65536];
__device__ float2 g_tw[512];           // tw[h+k] = exp(-i*pi*k/h)
__device__ float2 g_SfA[256*512];      // rows natural, cols p-order
__device__ float2 g_Sf [512*512];      // pi-order along u, p-order along v
__device__ float2 g_F  [16*256*256];   // row-FFT result, natural
__device__ float2 g_KA [8*256*512];    // PACKED batch pairs; rows natural, cols p-order
__device__ float2 g_P  [8*256*512];    // PACKED; conv rows, cols p-order

__device__ __forceinline__ int rev4d8(int x){
  return ((x&3)<<6) | (((x>>2)&3)<<4) | (((x>>4)&3)<<2) | ((x>>6)&3);
}
__device__ __forceinline__ float2 cadd(float2 a, float2 b){ return make_float2(a.x+b.x, a.y+b.y); }
__device__ __forceinline__ float2 csub(float2 a, float2 b){ return make_float2(a.x-b.x, a.y-b.y); }
__device__ __forceinline__ float2 cmul(float2 a, float2 b){ return make_float2(a.x*b.x - a.y*b.y, a.x*b.y + a.y*b.x); }
__device__ __forceinline__ float2 cmulj(float2 a, float2 b){ return make_float2(a.x*b.x + a.y*b.y, a.y*b.x - a.x*b.y); }
__device__ __forceinline__ float2 addi(float2 a, float2 b){ return make_float2(a.x - b.y, a.y + b.x); }
__device__ __forceinline__ float2 subi(float2 a, float2 b){ return make_float2(a.x + b.y, a.y - b.x); }

#define LIDX(x) ((x) + ((x)>>2))
#define OUT_W(idx, val) do{ int _i = (idx); if ((unsigned)_i < (unsigned)osz) out[_i] = (val); }while(0)

// ---- forward mid stages q=32,8,2 (512-pt, lanes r=0..127, padded split-LDS) ----
__device__ __forceinline__ void mid4f_512(float* re, float* im, int r){
  #pragma unroll
  for (int q = 32; q >= 2; q >>= 2){
    __syncthreads();
    int k = r & (q-1);
    int base = ((r - k) << 2) + k;
    int a0=LIDX(base), a1=LIDX(base+q), a2=LIDX(base+2*q), a3=LIDX(base+3*q);
    float x0r=re[a0], x0i=im[a0], x1r=re[a1], x1i=im[a1];
    float x2r=re[a2], x2i=im[a2], x3r=re[a3], x3i=im[a3];
    float t0r=x0r+x2r, t0i=x0i+x2i, t1r=x0r-x2r, t1i=x0i-x2i;
    float t2r=x1r+x3r, t2i=x1i+x3i, t3r=x1r-x3r, t3i=x1i-x3i;
    float y0r=t0r+t2r, y0i=t0i+t2i, y2r=t0r-t2r, y2i=t0i-t2i;
    float y1r=t1r+t3i, y1i=t1i-t3r;
    float y3r=t1r-t3i, y3i=t1i+t3r;
    float2 w1=g_tw[2*q+k], w2=g_tw[q+k];
    float w3r=w1.x*w2.x-w1.y*w2.y, w3i=w1.x*w2.y+w1.y*w2.x;
    re[a0]=y0r; im[a0]=y0i;
    re[a1]=y1r*w1.x-y1i*w1.y; im[a1]=y1r*w1.y+y1i*w1.x;
    re[a2]=y2r*w2.x-y2i*w2.y; im[a2]=y2r*w2.y+y2i*w2.x;
    re[a3]=y3r*w3r-y3i*w3i;  im[a3]=y3r*w3i+y3i*w3r;
  }
  __syncthreads();
}

// ---- inverse (DIT) mid stages q=2,8,32 ----
__device__ __forceinline__ void mid4i_512(float* re, float* im, int r){
  #pragma unroll
  for (int q = 2; q <= 32; q <<= 2){
    __syncthreads();
    int k = r & (q-1);
    int base = ((r - k) << 2) + k;
    int a0=LIDX(base), a1=LIDX(base+q), a2=LIDX(base+2*q), a3=LIDX(base+3*q);
    float z0r=re[a0], z0i=im[a0], z1r=re[a1], z1i=im[a1];
    float z2r=re[a2], z2i=im[a2], z3r=re[a3], z3i=im[a3];
    float2 w1=g_tw[2*q+k], w2=g_tw[q+k];
    float w3r=w1.x*w2.x-w1.y*w2.y, w3i=w1.x*w2.y+w1.y*w2.x;
    float b1r = z1r*w1.x + z1i*w1.y, b1i = z1i*w1.x - z1r*w1.y;
    float b2r = z2r*w2.x + z2i*w2.y, b2i = z2i*w2.x - z2r*w2.y;
    float b3r = z3r*w3r + z3i*w3i,  b3i = z3i*w3r - z3r*w3i;
    float u0r=z0r+b2r, u0i=z0i+b2i, u1r=z0r-b2r, u1i=z0i-b2i;
    float u2r=b1r+b3r, u2i=b1i+b3i, u3r=b1r-b3r, u3i=b1i-b3i;
    re[a0]=u0r+u2r; im[a0]=u0i+u2i;
    re[a1]=u1r-u3i; im[a1]=u1i+u3r;
    re[a2]=u0r-u2r; im[a2]=u0i-u2i;
    re[a3]=u1r+u3i; im[a3]=u1i-u3r;
  }
  __syncthreads();
}

// ================= L1: init (tw + separable PE) + norm1 =================
__global__ __launch_bounds__(256) void k_L1(const float* __restrict__ gw0,
                                            const float* __restrict__ gb0,
                                            const float* __restrict__ x){
  int bid = blockIdx.x;
  if (bid < 66){
    int t = bid*256 + threadIdx.x;
    if (t < 512){
      if (t == 0){ g_tw[0] = make_float2(1.f, 0.f); return; }
      int h = 1 << (31 - __clz(t));
      int k = t - h;
      double a = -M_PI * (double)k / (double)h;
      g_tw[t] = make_float2((float)cos(a), (float)sin(a));
      return;
    }
    int t2 = t - 512;
    if (t2 >= 16384) return;
    int isG = t2 >> 13;
    int pos = (t2 >> 5) & 255;
    int ch = t2 & 31;
    float xx = (float)(-1.0 + (2.0 * pos) / 255.0);
    float s1, c1; sincosf(xx, &s1, &c1);
    float s = s1, c = c1;
    float acc = isG ? 0.f : gb0[ch];
    #pragma unroll
    for (int i = 1; i <= 15; i++){
      const float* wsin = gw0 + (4*(i-1) + isG)*32;
      const float* wcos = gw0 + (4*(i-1) + 2 + isG)*32;
      acc += s*wsin[ch] + c*wcos[ch];
      float ns = s*c1 + c*s1, nc = c*c1 - s*s1;
      s = ns; c = nc;
    }
    if (isG) g_Gy[pos*32 + ch] = acc;
    else     g_Fx[pos*32 + ch] = acc;
  } else {
    int b = bid - 66;
    int tid = threadIdx.x;
    float4 v = ((const float4*)x)[(size_t)b*256 + tid];
    float s = v.x*v.x + v.y*v.y + v.z*v.z + v.w*v.w;
    __shared__ float red[256];
    red[tid] = s; __syncthreads();
    for (int w = 128; w > 0; w >>= 1){ if (tid < w) red[tid] += red[tid+w]; __syncthreads(); }
    if (tid == 0) g_partial[b] = red[0];
  }
}

// ================= L2: gmlp + patch + norm2, 4 px/thread, LDS-staged weights =================
__device__ __forceinline__ void gmlp_body(int bid, float* sw, float* hb,
    const float* __restrict__ gw1, const float* __restrict__ gb1,
    const float* __restrict__ l1w, const float* __restrict__ l1b,
    const float* __restrict__ gw2, const float* __restrict__ gb2,
    const float* __restrict__ l2w, const float* __restrict__ l2b,
    const float* __restrict__ gw3, const float* __restrict__ gb3)
{
  int tid = threadIdx.x;
  #pragma unroll
  for (int i = 0; i < 4; i++){
    sw[tid + 256*i] = gw1[tid + 256*i];
    sw[1024 + tid + 256*i] = gw2[tid + 256*i];
  }
  __syncthreads();

  int waveid = tid >> 6, lane = tid & 63;
  int group = lane >> 3, j8 = lane & 7;
  int gidx = tid >> 3;
  int p0 = bid*128 + waveid*32 + group*4;
  int cb = 4*j8;

  // h0 -> hb
  #pragma unroll
  for (int u = 0; u < 4; u++){
    int p = p0 + u;
    int r = p >> 8, c = p & 255;
    float4 F4 = *(const float4*)&g_Fx[c*32 + cb];
    float4 G4 = *(const float4*)&g_Gy[r*32 + cb];
    hb[(u*32 + cb + 0)*33 + gidx] = F4.x+G4.x;
    hb[(u*32 + cb + 1)*33 + gidx] = F4.y+G4.y;
    hb[(u*32 + cb + 2)*33 + gidx] = F4.z+G4.z;
    hb[(u*32 + cb + 3)*33 + gidx] = F4.w+G4.w;
  }

  // layer1
  float4 b1v = *(const float4*)&gb1[cb];
  float h1[4][4];
  #pragma unroll
  for (int u=0;u<4;u++){ h1[u][0]=b1v.x; h1[u][1]=b1v.y; h1[u][2]=b1v.z; h1[u][3]=b1v.w; }
  #pragma unroll
  for (int k = 0; k < 32; k++){
    float4 w = *(const float4*)&sw[k*32 + cb];
    float a0 = hb[(0*32+k)*33 + gidx];
    float a1 = hb[(1*32+k)*33 + gidx];
    float a2 = hb[(2*32+k)*33 + gidx];
    float a3 = hb[(3*32+k)*33 + gidx];
    h1[0][0]+=a0*w.x; h1[0][1]+=a0*w.y; h1[0][2]+=a0*w.z; h1[0][3]+=a0*w.w;
    h1[1][0]+=a1*w.x; h1[1][1]+=a1*w.y; h1[1][2]+=a1*w.z; h1[1][3]+=a1*w.w;
    h1[2][0]+=a2*w.x; h1[2][1]+=a2*w.y; h1[2][2]+=a2*w.z; h1[2][3]+=a2*w.w;
    h1[3][0]+=a3*w.x; h1[3][1]+=a3*w.y; h1[3][2]+=a3*w.z; h1[3][3]+=a3*w.w;
  }
  {
    float4 lw = *(const float4*)&l1w[cb];
    float4 lb = *(const float4*)&l1b[cb];
    #pragma unroll
    for (int u=0;u<4;u++){
      float s = h1[u][0]+h1[u][1]+h1[u][2]+h1[u][3];
      s += __shfl_xor(s,1,8); s += __shfl_xor(s,2,8); s += __shfl_xor(s,4,8);
      float mean = s*(1.0f/32.0f);
      float d0=h1[u][0]-mean, d1=h1[u][1]-mean, d2=h1[u][2]-mean, d3=h1[u][3]-mean;
      float vv = d0*d0+d1*d1+d2*d2+d3*d3;
      vv += __shfl_xor(vv,1,8); vv += __shfl_xor(vv,2,8); vv += __shfl_xor(vv,4,8);
      float inv = rsqrtf(vv*(1.0f/32.0f) + 1e-5f);
      float t0=d0*inv*lw.x+lb.x, t1=d1*inv*lw.y+lb.y, t2=d2*inv*lw.z+lb.z, t3=d3*inv*lw.w+lb.w;
      t0 = (t0>0.f)?t0:0.01f*t0; t1 = (t1>0.f)?t1:0.01f*t1;
      t2 = (t2>0.f)?t2:0.01f*t2; t3 = (t3>0.f)?t3:0.01f*t3;
      hb[(u*32 + cb + 0)*33 + gidx] = t0;
      hb[(u*32 + cb + 1)*33 + gidx] = t1;
      hb[(u*32 + cb + 2)*33 + gidx] = t2;
      hb[(u*32 + cb + 3)*33 + gidx] = t3;
    }
  }

  // layer2
  float4 b2v = *(const float4*)&gb2[cb];
  float h2[4][4];
  #pragma unroll
  for (int u=0;u<4;u++){ h2[u][0]=b2v.x; h2[u][1]=b2v.y; h2[u][2]=b2v.z; h2[u][3]=b2v.w; }
  #pragma unroll
  for (int k = 0; k < 32; k++){
    float4 w = *(const float4*)&sw[1024 + k*32 + cb];
    float a0 = hb[(0*32+k)*33 + gidx];
    float a1 = hb[(1*32+k)*33 + gidx];
    float a2 = hb[(2*32+k)*33 + gidx];
    float a3 = hb[(3*32+k)*33 + gidx];
    h2[0][0]+=a0*w.x; h2[0][1]+=a0*w.y; h2[0][2]+=a0*w.z; h2[0][3]+=a0*w.w;
    h2[1][0]+=a1*w.x; h2[1][1]+=a1*w.y; h2[1][2]+=a1*w.z; h2[1][3]+=a1*w.w;
    h2[2][0]+=a2*w.x; h2[2][1]+=a2*w.y; h2[2][2]+=a2*w.z; h2[2][3]+=a2*w.w;
    h2[3][0]+=a3*w.x; h2[3][1]+=a3*w.y; h2[3][2]+=a3*w.z; h2[3][3]+=a3*w.w;
  }
  {
    float4 lw = *(const float4*)&l2w[cb];
    float4 lb = *(const float4*)&l2b[cb];
    #pragma unroll
    for (int u=0;u<4;u++){
      float s = h2[u][0]+h2[u][1]+h2[u][2]+h2[u][3];
      s += __shfl_xor(s,1,8); s += __shfl_xor(s,2,8); s += __shfl_xor(s,4,8);
      float mean = s*(1.0f/32.0f);
      float d0=h2[u][0]-mean, d1=h2[u][1]-mean, d2=h2[u][2]-mean, d3=h2[u][3]-mean;
      float vv = d0*d0+d1*d1+d2*d2+d3*d3;
      vv += __shfl_xor(vv,1,8); vv += __shfl_xor(vv,2,8); vv += __shfl_xor(vv,4,8);
      float inv = rsqrtf(vv*(1.0f/32.0f) + 1e-5f);
      float t0=d0*inv*lw.x+lb.x, t1=d1*inv*lw.y+lb.y, t2=d2*inv*lw.z+lb.z, t3=d3*inv*lw.w+lb.w;
      h2[u][0] = (t0>0.f)?t0:0.01f*t0; h2[u][1] = (t1>0.f)?t1:0.01f*t1;
      h2[u][2] = (t2>0.f)?t2:0.01f*t2; h2[u][3] = (t3>0.f)?t3:0.01f*t3;
    }
  }

  float4 w3v = *(const float4*)&gw3[cb];
  float b3 = gb3[0];
  #pragma unroll
  for (int u=0;u<4;u++){
    float pp = h2[u][0]*w3v.x + h2[u][1]*w3v.y + h2[u][2]*w3v.z + h2[u][3]*w3v.w;
    pp += __shfl_xor(pp,1,8); pp += __shfl_xor(pp,2,8); pp += __shfl_xor(pp,4,8);
    float phs = pp + b3;
    if (j8 == 0){
      float sp, cp; sincosf(phs, &sp, &cp);
      g_phs[p0+u] = phs;
      g_cs[p0+u] = make_float2(cp, sp);
    }
  }
}

__device__ __forceinline__ void patch_body(int bid, float* sw, float* hb,
    const float* __restrict__ pdata, const float* __restrict__ rw0, const float* __restrict__ rb0,
    const float* __restrict__ rw1, const float* __restrict__ rb1,
    const float* __restrict__ rw2, const float* __restrict__ rb2,
    float* out, int osz, int offIest)
{
  int tid = threadIdx.x;
  int p0 = bid*128 + (tid >> 6)*32 + ((tid & 63) >> 3)*4;
  int patch = p0 >> 14;

  const float* w0g = rw0 + patch*1024;
  const float* w1g = rw1 + patch*1024;
  #pragma unroll
  for (int i = 0; i < 4; i++){
    sw[tid + 256*i] = w0g[tid + 256*i];
    sw[1024 + tid + 256*i] = w1g[tid + 256*i];
  }
  __syncthreads();

  int lane = tid & 63;
  int j8 = lane & 7;
  int gidx = tid >> 3;
  int pl0 = p0 & 16383;
  int i = pl0 >> 7, jp = pl0 & 127;
  int i1 = min(i+1, 127);
  int cb = 4*j8;

  const float* base = pdata + (size_t)patch * 128*128*32;
  #pragma unroll
  for (int u = 0; u < 4; u++){
    int j = jp + u, j1 = min(j+1, 127);
    float4 a  = *(const float4*)&base[(i *128 + j )*32 + cb];
    float4 b  = *(const float4*)&base[(i *128 + j1)*32 + cb];
    float4 cc = *(const float4*)&base[(i1*128 + j )*32 + cb];
    float4 d  = *(const float4*)&base[(i1*128 + j1)*32 + cb];
    hb[(u*32 + cb + 0)*33 + gidx] = 0.25f*(a.x+b.x+cc.x+d.x);
    hb[(u*32 + cb + 1)*33 + gidx] = 0.25f*(a.y+b.y+cc.y+d.y);
    hb[(u*32 + cb + 2)*33 + gidx] = 0.25f*(a.z+b.z+cc.z+d.z);
    hb[(u*32 + cb + 3)*33 + gidx] = 0.25f*(a.w+b.w+cc.w+d.w);
  }

  float4 b0v = *(const float4*)&rb0[patch*32 + cb];
  float h[4][4];
  #pragma unroll
  for (int u=0;u<4;u++){ h[u][0]=b0v.x; h[u][1]=b0v.y; h[u][2]=b0v.z; h[u][3]=b0v.w; }
  #pragma unroll
  for (int k = 0; k < 32; k++){
    float4 w = *(const float4*)&sw[k*32 + cb];
    float a0 = hb[(0*32+k)*33 + gidx];
    float a1 = hb[(1*32+k)*33 + gidx];
    float a2 = hb[(2*32+k)*33 + gidx];
    float a3 = hb[(3*32+k)*33 + gidx];
    h[0][0]+=a0*w.x; h[0][1]+=a0*w.y; h[0][2]+=a0*w.z; h[0][3]+=a0*w.w;
    h[1][0]+=a1*w.x; h[1][1]+=a1*w.y; h[1][2]+=a1*w.z; h[1][3]+=a1*w.w;
    h[2][0]+=a2*w.x; h[2][1]+=a2*w.y; h[2][2]+=a2*w.z; h[2][3]+=a2*w.w;
    h[3][0]+=a3*w.x; h[3][1]+=a3*w.y; h[3][2]+=a3*w.z; h[3][3]+=a3*w.w;
  }
  #pragma unroll
  for (int u=0;u<4;u++){
    hb[(u*32 + cb + 0)*33 + gidx] = fmaxf(h[u][0],0.f);
    hb[(u*32 + cb + 1)*33 + gidx] = fmaxf(h[u][1],0.f);
    hb[(u*32 + cb + 2)*33 + gidx] = fmaxf(h[u][2],0.f);
    hb[(u*32 + cb + 3)*33 + gidx] = fmaxf(h[u][3],0.f);
  }

  float4 b1v = *(const float4*)&rb1[patch*32 + cb];
  float g[4][4];
  #pragma unroll
  for (int u=0;u<4;u++){ g[u][0]=b1v.x; g[u][1]=b1v.y; g[u][2]=b1v.z; g[u][3]=b1v.w; }
  #pragma unroll
  for (int k = 0; k < 32; k++){
    float4 w = *(const float4*)&sw[1024 + k*32 + cb];
    float a0 = hb[(0*32+k)*33 + gidx];
    float a1 = hb[(1*32+k)*33 + gidx];
    float a2 = hb[(2*32+k)*33 + gidx];
    float a3 = hb[(3*32+k)*33 + gidx];
    g[0][0]+=a0*w.x; g[0][1]+=a0*w.y; g[0][2]+=a0*w.z; g[0][3]+=a0*w.w;
    g[1][0]+=a1*w.x; g[1][1]+=a1*w.y; g[1][2]+=a1*w.z; g[1][3]+=a1*w.w;
    g[2][0]+=a2*w.x; g[2][1]+=a2*w.y; g[2][2]+=a2*w.z; g[2][3]+=a2*w.w;
    g[3][0]+=a3*w.x; g[3][1]+=a3*w.y; g[3][2]+=a3*w.z; g[3][3]+=a3*w.w;
  }

  float4 w2v = *(const float4*)&rw2[patch*32 + cb];
  float b2s = rb2[patch];
  #pragma unroll
  for (int u=0;u<4;u++){
    float o = fmaxf(g[u][0],0.f)*w2v.x + fmaxf(g[u][1],0.f)*w2v.y
            + fmaxf(g[u][2],0.f)*w2v.z + fmaxf(g[u][3],0.f)*w2v.w;
    o += __shfl_xor(o,1,8); o += __shfl_xor(o,2,8); o += __shfl_xor(o,4,8);
    o += b2s;
    if (j8 == 0){
      int pr = (patch >> 1)*128 + i;
      int pc = (patch & 1)*128 + jp + u;
      g_I[pr*256 + pc] = o;
      OUT_W(offIest + pr*256 + pc, o);
    }
  }
}

__device__ __forceinline__ void norm2_body(){
  int tid = threadIdx.x;
  int b = tid >> 4, l = tid & 15;
  float s = 0.f;
  #pragma unroll
  for (int j = 0; j < 4; j++) s += g_partial[b*64 + l + 16*j];
  #pragma unroll
  for (int d = 8; d > 0; d >>= 1) s += __shfl_down(s, d, 16);
  if (l == 0) g_norms[b] = 65536.0f * s;
}

__global__ __launch_bounds__(256) void k_L2(
    const float* __restrict__ gw1, const float* __restrict__ gb1,
    const float* __restrict__ l1w, const float* __restrict__ l1b,
    const float* __restrict__ gw2, const float* __restrict__ gb2,
    const float* __restrict__ l2w, const float* __restrict__ l2b,
    const float* __restrict__ gw3, const float* __restrict__ gb3,
    const float* __restrict__ pdata, const float* __restrict__ rw0, const float* __restrict__ rb0,
    const float* __restrict__ rw1, const float* __restrict__ rb1,
    const float* __restrict__ rw2, const float* __restrict__ rb2,
    float* out, int osz, int offIest)
{
  __shared__ float sw[2048];
  __shared__ float hb[4224];   // 128*33 floats
  int bid = blockIdx.x;
  if (bid < 512)       gmlp_body(bid, sw, hb, gw1, gb1, l1w, l1b, gw2, gb2, l2w, l2b, gw3, gb3);
  else if (bid < 1024) patch_body(bid-512, sw, hb, pdata, rw0, rb0, rw1, rb1, rw2, rb2, out, osz, offIest);
  else                 norm2_body();
}

// ================= L3: S_row + field_row + bcast =================
__device__ __forceinline__ void srow_body(int bid, float* sm){
  int t = threadIdx.x;
  int row = t >> 7, r = t & 127;
  int gr = bid*2 + row;
  float* rre = sm + row*640; float* rim = sm + 1280 + row*640;
  float A = g_I[gr*256 + r], B = g_I[gr*256 + r + 128];
  {
    float2 w1 = g_tw[256+r], w2 = g_tw[128+r];
    float w3r = w1.x*w2.x - w1.y*w2.y, w3i = w1.x*w2.y + w1.y*w2.x;
    float s = A + B, d = A - B;
    rre[LIDX(r)]     = s;                   rim[LIDX(r)]     = 0.f;
    rre[LIDX(r+128)] = A*w1.x + B*w1.y;     rim[LIDX(r+128)] = A*w1.y - B*w1.x;
    rre[LIDX(r+256)] = d*w2.x;              rim[LIDX(r+256)] = d*w2.y;
    rre[LIDX(r+384)] = A*w3r - B*w3i;       rim[LIDX(r+384)] = A*w3i + B*w3r;
  }
  mid4f_512(rre, rim, r);
  float2* Srow = &g_SfA[gr*512];
  #pragma unroll
  for (int h = 0; h < 2; h++){
    int g = r + 128*h;
    int a0 = LIDX(2*g), a1 = LIDX(2*g+1);
    float ar = rre[a0], ai = rim[a0], br = rre[a1], bi = rim[a1];
    *(float4*)&Srow[2*g] = make_float4(ar+br, ai+bi, ar-br, ai-bi);
  }
}

__device__ __forceinline__ void frow_body(int bid, const float* __restrict__ x, float* sm){
  int t = threadIdx.x;
  int row = t >> 6, l = t & 63;
  int gr = bid*4 + row;
  int b = gr >> 8, xr = gr & 255;
  float* rre = sm + row*320; float* rim = sm + 1280 + row*320;
  const float* xrow = x + ((size_t)b*256 + xr)*256;
  const float2* csrow = g_cs + xr*256;

  float x0r,x0i,x1r,x1i,x2r,x2i,x3r,x3i;
  { float xv=xrow[l];      float2 cs=csrow[l];      x0r=xv*cs.x; x0i=xv*cs.y; }
  { float xv=xrow[l+64];   float2 cs=csrow[l+64];   x1r=xv*cs.x; x1i=xv*cs.y; }
  { float xv=xrow[l+128];  float2 cs=csrow[l+128];  x2r=xv*cs.x; x2i=xv*cs.y; }
  { float xv=xrow[l+192];  float2 cs=csrow[l+192];  x3r=xv*cs.x; x3i=xv*cs.y; }
  {
    float t0r=x0r+x2r, t0i=x0i+x2i, t1r=x0r-x2r, t1i=x0i-x2i;
    float t2r=x1r+x3r, t2i=x1i+x3i, t3r=x1r-x3r, t3i=x1i-x3i;
    float y0r=t0r+t2r, y0i=t0i+t2i, y2r=t0r-t2r, y2i=t0i-t2i;
    float y1r=t1r+t3i, y1i=t1i-t3r;
    float y3r=t1r-t3i, y3i=t1i+t3r;
    float2 w1=g_tw[128+l], w2=g_tw[64+l];
    float w3r=w1.x*w2.x-w1.y*w2.y, w3i=w1.x*w2.y+w1.y*w2.x;
    rre[LIDX(l)]     = y0r;                     rim[LIDX(l)]     = y0i;
    rre[LIDX(l+64)]  = y1r*w1.x-y1i*w1.y;       rim[LIDX(l+64)]  = y1r*w1.y+y1i*w1.x;
    rre[LIDX(l+128)] = y2r*w2.x-y2i*w2.y;       rim[LIDX(l+128)] = y2r*w2.y+y2i*w2.x;
    rre[LIDX(l+192)] = y3r*w3r-y3i*w3i;         rim[LIDX(l+192)] = y3r*w3i+y3i*w3r;
  }
  #pragma unroll
  for (int q = 16; q >= 4; q >>= 2){
    __syncthreads();
    int k = l & (q-1);
    int base = ((l - k) << 2) + k;
    int a0=LIDX(base), a1=LIDX(base+q), a2=LIDX(base+2*q), a3=LIDX(base+3*q);
    float z0r=rre[a0], z0i=rim[a0], z1r=rre[a1], z1i=rim[a1];
    float z2r=rre[a2], z2i=rim[a2], z3r=rre[a3], z3i=rim[a3];
    float t0r=z0r+z2r, t0i=z0i+z2i, t1r=z0r-z2r, t1i=z0i-z2i;
    float t2r=z1r+z3r, t2i=z1i+z3i, t3r=z1r-z3r, t3i=z1i-z3i;
    float y0r=t0r+t2r, y0i=t0i+t2i, y2r=t0r-t2r, y2i=t0i-t2i;
    float y1r=t1r+t3i, y1i=t1i-t3r;
    float y3r=t1r-t3i, y3i=t1i+t3r;
    float2 w1=g_tw[2*q+k], w2=g_tw[q+k];
    float w3r=w1.x*w2.x-w1.y*w2.y, w3i=w1.x*w2.y+w1.y*w2.x;
    rre[a0]=y0r; rim[a0]=y0i;
    rre[a1]=y1r*w1.x-y1i*w1.y; rim[a1]=y1r*w1.y+y1i*w1.x;
    rre[a2]=y2r*w2.x-y2i*w2.y; rim[a2]=y2r*w2.y+y2i*w2.x;
    rre[a3]=y3r*w3r-y3i*w3i;  rim[a3]=y3r*w3i+y3i*w3r;
  }
  __syncthreads();
  {
    int a0=LIDX(4*l), a1=LIDX(4*l+1), a2=LIDX(4*l+2), a3=LIDX(4*l+3);
    float z0r=rre[a0], z0i=rim[a0], z1r=rre[a1], z1i=rim[a1];
    float z2r=rre[a2], z2i=rim[a2], z3r=rre[a3], z3i=rim[a3];
    float t0r=z0r+z2r, t0i=z0i+z2i, t1r=z0r-z2r, t1i=z0i-z2i;
    float t2r=z1r+z3r, t2i=z1i+z3i, t3r=z1r-z3r, t3i=z1i-z3i;
    float2* Frow = &g_F[((size_t)b*256 + xr)*256];
    Frow[rev4d8(4*l)]   = make_float2(t0r+t2r, t0i+t2i);
    Frow[rev4d8(4*l+1)] = make_float2(t1r+t3i, t1i-t3r);
    Frow[rev4d8(4*l+2)] = make_float2(t0r-t2r, t0i-t2i);
    Frow[rev4d8(4*l+3)] = make_float2(t1r-t3i, t1i+t3r);
  }
}

__device__ __forceinline__ void bcast_body(int bid, float* out, int osz, int offG, int offPhs, int interleaved){
  int idx = bid*256 + threadIdx.x;
  int p = idx & 65535, b = idx >> 16;
  float phs = g_phs[p];
  float2 cs = g_cs[p];
  OUT_W(offPhs + b*65536 + p, phs);
  if (interleaved){
    int gi = offG + 2*(b*65536 + p);
    if (gi + 1 < osz) *(float2*)(out + gi) = cs;
  } else {
    OUT_W(offG + b*65536 + p, cs.x);
  }
}

__global__ __launch_bounds__(256) void k_L3(const float* __restrict__ x, float* out, int osz,
                                            int offG, int offPhs, int interleaved){
  __shared__ float sm[2560];
  int bid = blockIdx.x;
  if (bid < 128)       srow_body(bid, sm);
  else if (bid < 1152) frow_body(bid-128, x, sm);
  else                 bcast_body(bid-1152, out, osz, offG, offPhs, interleaved);
}

// ================= L4: S_col + field_col(+mag->d_out) =================
__device__ __forceinline__ void fold512_load(const float2* src, float2* buf, int c, int rr){
  for (int i = rr; i < 128; i += 32){
    float2 a = src[(size_t)i*512];
    float2 b = src[(size_t)(i+128)*512];
    float2 w1 = g_tw[256+i], w2 = g_tw[128+i];
    float2 w3 = cmul(w1, w2);
    buf[i*9+c]       = cadd(a,b);
    buf[(i+128)*9+c] = cmul(subi(a,b), w1);
    buf[(i+256)*9+c] = cmul(csub(a,b), w2);
    buf[(i+384)*9+c] = cmul(addi(a,b), w3);
  }
}

__device__ __forceinline__ void dif4_stages_512(float2* buf, int c, int rr){
  #pragma unroll
  for (int q = 32; q >= 2; q >>= 2){
    __syncthreads();
    for (int g = rr; g < 128; g += 32){
      int k = g & (q-1);
      int base = ((g - k) << 2) + k;
      float2 x0 = buf[base*9+c], x1 = buf[(base+q)*9+c];
      float2 x2 = buf[(base+2*q)*9+c], x3 = buf[(base+3*q)*9+c];
      float2 t0=cadd(x0,x2), t1=csub(x0,x2), t2=cadd(x1,x3), t3=csub(x1,x3);
      float2 y0=cadd(t0,t2), y1=subi(t1,t3), y2=csub(t0,t2), y3=addi(t1,t3);
      float2 w1 = g_tw[2*q+k], w2 = g_tw[q+k];
      float2 w3 = cmul(w1,w2);
      buf[base*9+c]       = y0;
      buf[(base+q)*9+c]   = cmul(y1,w1);
      buf[(base+2*q)*9+c] = cmul(y2,w2);
      buf[(base+3*q)*9+c] = cmul(y3,w3);
    }
  }
}

__device__ __forceinline__ void scol_body(int bid, float2* buf){
  int v0 = bid << 3;
  int tid = threadIdx.x, c = tid & 7, rr = tid >> 3;
  int v = v0 + c;
  fold512_load(&g_SfA[v], buf, c, rr);
  dif4_stages_512(buf, c, rr);
  __syncthreads();
  for (int g = rr; g < 256; g += 32){
    int i0 = 2*g;
    float2 a = buf[i0*9+c], b = buf[(i0+1)*9+c];
    g_Sf[(size_t)i0*512 + v]     = cadd(a,b);
    g_Sf[(size_t)(i0+1)*512 + v] = csub(a,b);
  }
}

__device__ __forceinline__ void fcol_body(int bid, float2* buf, float* out, int osz, int offKer){
  int b = bid >> 5, v0 = (bid & 31) << 3;
  int tid = threadIdx.x, c = tid & 7, rr = tid >> 3;
  const float2* Fr = &g_F[(size_t)b*65536 + v0 + c];
  for (int r = rr; r < 256; r += 32) buf[r*9+c] = Fr[(size_t)r*256];
  #pragma unroll
  for (int q = 64; q >= 1; q >>= 2){
    __syncthreads();
    for (int g = rr; g < 64; g += 32){
      int k = g & (q-1);
      int base = ((g - k) << 2) + k;
      float2 x0 = buf[base*9+c], x1 = buf[(base+q)*9+c];
      float2 x2 = buf[(base+2*q)*9+c], x3 = buf[(base+3*q)*9+c];
      float2 t0=cadd(x0,x2), t1=csub(x0,x2), t2=cadd(x1,x3), t3=csub(x1,x3);
      float2 y0=cadd(t0,t2), y1=subi(t1,t3), y2=csub(t0,t2), y3=addi(t1,t3);
      if (q > 1){
        float2 w1 = g_tw[2*q+k], w2 = g_tw[q+k];
        float2 w3 = cmul(w1,w2);
        y1 = cmul(y1,w1); y2 = cmul(y2,w2); y3 = cmul(y3,w3);
      }
      buf[base*9+c]=y0; buf[(base+q)*9+c]=y1; buf[(base+2*q)*9+c]=y2; buf[(base+3*q)*9+c]=y3;
    }
  }
  __syncthreads();
  float invn = 1.0f / g_norms[b];
  int v = v0 + c;
  int e = (127 - v) & 255;
  for (int p = rr; p < 256; p += 32){
    float2 f = buf[p*9+c];
    int a = rev4d8(p);
    int rt = (127 - a) & 255;
    float kv = (f.x*f.x + f.y*f.y) * invn;
    OUT_W(offKer + b*65536 + rt*256 + e, kv);
  }
}

__global__ __launch_bounds__(256) void k_L4(float* out, int osz, int offKer){
  __shared__ float2 buf[512*9];
  int bid = blockIdx.x;
  if (bid < 64) scol_body(bid, buf);
  else          fcol_body(bid-64, buf, out, osz, offKer);
}

// ============ L5: packed kernel-row FFT (reads kernel from d_out) ============
__global__ __launch_bounds__(256) void k_krow(const float* __restrict__ out_ro, int osz, int offKer){
  __shared__ float re[2*640], im[2*640];
  int t = threadIdx.x;
  int row = t >> 7, r = t & 127;
  int gr = blockIdx.x*2 + row;            // 0..2047 packed rows
  int q = gr >> 8, kr = gr & 255;
  int b0 = 2*q, b1 = 2*q + 1;
  float* rre = re + row*640; float* rim = im + row*640;

  const float* k0 = out_ro + offKer + b0*65536 + kr*256;
  const float* k1 = out_ro + offKer + b1*65536 + kr*256;
  float2 zA = make_float2(k0[r],      k1[r]);
  float2 zB = make_float2(k0[r+128],  k1[r+128]);

  {
    float2 w1 = g_tw[256+r], w2 = g_tw[128+r];
    float2 w3 = cmul(w1, w2);
    float2 p0 = cadd(zA, zB);
    float2 p1 = cmul(subi(zA, zB), w1);
    float2 p2 = cmul(csub(zA, zB), w2);
    float2 p3 = cmul(addi(zA, zB), w3);
    rre[LIDX(r)]     = p0.x; rim[LIDX(r)]     = p0.y;
    rre[LIDX(r+128)] = p1.x; rim[LIDX(r+128)] = p1.y;
    rre[LIDX(r+256)] = p2.x; rim[LIDX(r+256)] = p2.y;
    rre[LIDX(r+384)] = p3.x; rim[LIDX(r+384)] = p3.y;
  }
  mid4f_512(rre, rim, r);
  float2* KArow = &g_KA[((size_t)q*256 + kr)*512];
  #pragma unroll
  for (int h = 0; h < 2; h++){
    int g = r + 128*h;
    int a0 = LIDX(2*g), a1 = LIDX(2*g+1);
    float ar = rre[a0], ai = rim[a0], br = rre[a1], bi = rim[a1];
    *(float4*)&KArow[2*g] = make_float4(ar+br, ai+bi, ar-br, ai-bi);
  }
}

// ============ L6: fused col pass (8 packed images) ============
__global__ __launch_bounds__(256) void k_col_mul_inv(){
  __shared__ float2 buf[512*9];
  int bi = blockIdx.x >> 6, v0 = (blockIdx.x & 63) << 3;
  int tid = threadIdx.x, c = tid & 7, rr = tid >> 3;
  int v = v0 + c;

  fold512_load(&g_KA[((size_t)bi*256)*512 + v], buf, c, rr);
  dif4_stages_512(buf, c, rr);

  __syncthreads();
  for (int g = rr; g < 256; g += 32){
    int i0 = 2*g;
    float2 a = buf[i0*9+c], b = buf[(i0+1)*9+c];
    float2 y0 = cadd(a,b), y1 = csub(a,b);
    float2 s0 = g_Sf[(size_t)i0*512 + v];
    float2 s1 = g_Sf[(size_t)(i0+1)*512 + v];
    float2 z0 = cmul(y0,s0), z1 = cmul(y1,s1);
    buf[i0*9+c]     = cadd(z0,z1);
    buf[(i0+1)*9+c] = csub(z0,z1);
  }

  #pragma unroll
  for (int q = 2; q <= 32; q <<= 2){
    __syncthreads();
    for (int g = rr; g < 128; g += 32){
      int k = g & (q-1);
      int base = ((g - k) << 2) + k;
      float2 z0 = buf[base*9+c], z1 = buf[(base+q)*9+c];
      float2 z2 = buf[(base+2*q)*9+c], z3 = buf[(base+3*q)*9+c];
      float2 w1 = g_tw[2*q+k], w2 = g_tw[q+k];
      float2 w3 = cmul(w1,w2);
      z1 = cmulj(z1,w1); z2 = cmulj(z2,w2); z3 = cmulj(z3,w3);
      float2 u0=cadd(z0,z2), u1=csub(z0,z2), u2=cadd(z1,z3), u3=csub(z1,z3);
      buf[base*9+c]       = cadd(u0,u2);
      buf[(base+q)*9+c]   = addi(u1,u3);
      buf[(base+2*q)*9+c] = csub(u0,u2);
      buf[(base+3*q)*9+c] = subi(u1,u3);
    }
  }

  __syncthreads();
  for (int i = rr; i < 128; i += 32){
    float2 z0 = buf[i*9+c], z1 = buf[(i+128)*9+c];
    float2 z2 = buf[(i+256)*9+c], z3 = buf[(i+384)*9+c];
    float2 w1 = g_tw[256+i], w2 = g_tw[128+i];
    float2 w3 = cmul(w1,w2);
    z1 = cmulj(z1,w1); z2 = cmulj(z2,w2); z3 = cmulj(z3,w3);
    float2 u0=cadd(z0,z2), u1=csub(z0,z2), u2=cadd(z1,z3), u3=csub(z1,z3);
    g_P[((size_t)bi*256 + i)*512 + v]       = addi(u1,u3);
    g_P[((size_t)bi*256 + i + 128)*512 + v] = csub(u0,u2);
  }
}

// ============ L7: packed inverse row FFT; Re->batch 2q, Im->batch 2q+1 ============
__global__ __launch_bounds__(256) void k_ifft_row(float* out, int osz){
  __shared__ float re[2*640], im[2*640];
  int t = threadIdx.x;
  int row = t >> 7, r = t & 127;
  int gr = blockIdx.x*2 + row;            // 0..2047 packed rows
  int q = gr >> 8, ri = gr & 255;
  int b0 = 2*q, b1 = 2*q + 1;
  float* rre = re + row*640; float* rim = im + row*640;
  const float2* Prow = &g_P[((size_t)q*256 + ri)*512];

  #pragma unroll
  for (int h = 0; h < 2; h++){
    int g = r + 128*h;
    float4 pq = *(const float4*)&Prow[2*g];
    rre[LIDX(2*g)]   = pq.x + pq.z;  rim[LIDX(2*g)]   = pq.y + pq.w;
    rre[LIDX(2*g+1)] = pq.x - pq.z;  rim[LIDX(2*g+1)] = pq.y - pq.w;
  }
  mid4i_512(rre, rim, r);
  {
    int a0=LIDX(r), a1=LIDX(r+128), a2=LIDX(r+256), a3=LIDX(r+384);
    float z0r=rre[a0], z0i=rim[a0];
    float z1r=rre[a1], z1i=rim[a1];
    float z2r=rre[a2], z2i=rim[a2];
    float z3r=rre[a3], z3i=rim[a3];
    float2 w1 = g_tw[256+r], w2 = g_tw[128+r];
    float w3r=w1.x*w2.x-w1.y*w2.y, w3i=w1.x*w2.y+w1.y*w2.x;
    float b1r = z1r*w1.x + z1i*w1.y, b1i = z1i*w1.x - z1r*w1.y;
    float b2r = z2r*w2.x + z2i*w2.y, b2i = z2i*w2.x - z2r*w2.y;
    float b3r = z3r*w3r + z3i*w3i,  b3i = z3i*w3r - z3r*w3i;
    float u0r = z0r + b2r, u0i = z0i + b2i;
    float u1r = z0r - b2r, u1i = z0i - b2i;
    float u2r = b1r + b3r, u2i = b1i + b3i;
    float u3r = b1r - b3r, u3i = b1i - b3i;
    const float sc = 1.0f / 262144.0f;
    OUT_W(b0*65536 + ri*256 + r,       (u1r - u3i) * sc);
    OUT_W(b1*65536 + ri*256 + r,       (u1i + u3r) * sc);
    OUT_W(b0*65536 + ri*256 + r + 128, (u0r - u2r) * sc);
    OUT_W(b1*65536 + ri*256 + r + 128, (u0i - u2i) * sc);
  }
}

extern "C" void kernel_launch(void* const* d_in, const int* in_sizes, int n_in,
                              void* d_out, int out_size, void* d_ws, size_t ws_size,
                              hipStream_t stream) {
  static const int expect[21] = {
    16*65536, 16, 4*128*128*32,
    4*32*32, 4*32, 4*32*32, 4*32, 4*32, 4,
    60*32, 32, 32*32, 32, 32, 32, 32*32, 32, 32, 32, 32, 1
  };
  if (n_in < 21) return;
  for (int i = 0; i < 21; i++) if (in_sizes[i] != expect[i]) return;

  const float* x_batch = (const float*)d_in[0];
  const float* pdata = (const float*)d_in[2];
  const float* rw0 = (const float*)d_in[3];
  const float* rb0 = (const float*)d_in[4];
  const float* rw1 = (const float*)d_in[5];
  const float* rb1 = (const float*)d_in[6];
  const float* rw2 = (const float*)d_in[7];
  const float* rb2 = (const float*)d_in[8];
  const float* gw0 = (const float*)d_in[9];
  const float* gb0 = (const float*)d_in[10];
  const float* gw1 = (const float*)d_in[11];
  const float* gb1 = (const float*)d_in[12];
  const float* l1w = (const float*)d_in[13];
  const float* l1b = (const float*)d_in[14];
  const float* gw2 = (const float*)d_in[15];
  const float* gb2 = (const float*)d_in[16];
  const float* l2w = (const float*)d_in[17];
  const float* l2b = (const float*)d_in[18];
  const float* gw3 = (const float*)d_in[19];
  const float* gb3 = (const float*)d_in[20];

  float* out = (float*)d_out;

  int interleaved = (out_size >= 5308416) ? 1 : 0;
  int offKer  = 1048576;
  int offG    = 2097152;
  int offPhs  = interleaved ? 4194304 : 3145728;
  int offIest = interleaved ? 5242880 : 4194304;

  k_L1<<<1090, 256, 0, stream>>>(gw0, gb0, x_batch);
  k_L2<<<1025, 256, 0, stream>>>(gw1, gb1, l1w, l1b, gw2, gb2, l2w, l2b, gw3, gb3,
                                 pdata, rw0, rb0, rw1, rb1, rw2, rb2, out, out_size, offIest);
  k_L3<<<5248, 256, 0, stream>>>(x_batch, out, out_size, offG, offPhs, interleaved);
  k_L4<<<576, 256, 0, stream>>>(out, out_size, offKer);
  k_krow<<<1024, 256, 0, stream>>>(out, out_size, offKer);
  k_col_mul_inv<<<512, 256, 0, stream>>>();
  k_ifft_row<<<1024, 256, 0, stream>>>(out, out_size);
}